// Round 2
// baseline (117.800 us; speedup 1.0000x reference)
//
#include <hip/hip_runtime.h>
#include <hip/hip_bf16.h>
#include <stdint.h>

#define N_TOT  8192
#define BHALF  4096
#define DDIM   128
#define NSPLIT 16
#define LOG2E  1.4426950408889634f
#define LN2    0.6931471805599453f

typedef short bf16x8 __attribute__((ext_vector_type(8)));
typedef float f32x4  __attribute__((ext_vector_type(4)));

__device__ __forceinline__ float ex2(float x) { return __builtin_amdgcn_exp2f(x); }

#define SCALE_C 3.798282440185f   /* sqrt(10*log2(e)): MFMA emits t = s*log2e */

__device__ __forceinline__ ushort2 cvt2(float a, float b) {
    __hip_bfloat162 h = __float22bfloat162_rn(make_float2(a, b));
    return *reinterpret_cast<ushort2*>(&h);
}

__device__ __forceinline__ bf16x8 cvt8(float4 lo, float4 hi) {
    union { bf16x8 v; ushort2 u[4]; } r;
    r.u[0] = cvt2(lo.x * SCALE_C, lo.y * SCALE_C);
    r.u[1] = cvt2(lo.z * SCALE_C, lo.w * SCALE_C);
    r.u[2] = cvt2(hi.x * SCALE_C, hi.y * SCALE_C);
    r.u[3] = cvt2(hi.z * SCALE_C, hi.w * SCALE_C);
    return r.v;
}

__device__ __forceinline__ void gload16(const void* g, void* l) {
    __builtin_amdgcn_global_load_lds(
        (const __attribute__((address_space(1))) void*)g,
        (__attribute__((address_space(3))) void*)l, 16, 0, 0);
}

// K0: z fp32 -> zb bf16 (*SCALE_C pre-folded), pre-XOR-swizzled (rule #21).
// Also: pos[r] = zi[r].zj[r] fp32 dot (16-lane shfl tree), cnt zeroing, out init.
__launch_bounds__(256)
__global__ void k_prep(const float* __restrict__ zi, const float* __restrict__ zj,
                       unsigned short* __restrict__ zb, float* __restrict__ pos,
                       int* __restrict__ cnt, float* __restrict__ out) {
    if (blockIdx.x == 0 && threadIdx.x < 32) {
        cnt[threadIdx.x] = 0;
        if (threadIdx.x == 0) out[0] = 0.f;
    }
    int gid = blockIdx.x * 256 + threadIdx.x;               // 8192 rows x 16 groups
    int row = gid >> 4, g = gid & 15;
    const float* rp = (row < BHALF) ? zi + row * DDIM : zj + (row - BHALF) * DDIM;
    float4 lo = *reinterpret_cast<const float4*>(rp + g * 8);
    float4 hi = *reinterpret_cast<const float4*>(rp + g * 8 + 4);
    int slot = g ^ (row & 7);
    *reinterpret_cast<bf16x8*>(&zb[row * DDIM + slot * 8]) = cvt8(lo, hi);

    if (row < BHALF) {                     // wave-uniform: blocks 0..255 only
        const float* qp = zj + row * DDIM + g * 8;
        float4 ql = *reinterpret_cast<const float4*>(qp);
        float4 qh = *reinterpret_cast<const float4*>(qp + 4);
        float d = lo.x * ql.x + lo.y * ql.y + lo.z * ql.z + lo.w * ql.w
                + hi.x * qh.x + hi.y * qh.y + hi.z * qh.z + hi.w * qh.w;
        #pragma unroll
        for (int msk = 1; msk < 16; msk <<= 1) d += __shfl_xor(d, msk, 64);
        if (g == 0) pos[row] = d;          // raw dot; x10 applied at merge
    }
}

// K1: streaming online-logsumexp over sim = (z z^T)/T rows, bf16 MFMA.
// Grid 512 = 32 row-blocks x 16 col-splits. The last block to finish a
// row-block (device-scope counter) merges the 16 partials inline
// (threadfence-reduction pattern) -- no separate k_finish dispatch.
__launch_bounds__(512, 4)
__global__ void k_main(const unsigned short* __restrict__ zb,
                       float* __restrict__ pm, float* __restrict__ pl,
                       const float* __restrict__ pos, int* __restrict__ cnt,
                       float* __restrict__ out) {
    __shared__ unsigned short lds[2][64 * 128];   // 2 x 16 KB
    const int tid = threadIdx.x;
    const int w = tid >> 6, lane = tid & 63;
    const int q = lane >> 4, ln = lane & 15;
    const int rb = blockIdx.x >> 4, cs = blockIdx.x & 15;
    const int rowBase = rb * 256 + w * 32;
    const int colBase = cs * 512;

    // A fragments: direct bf16 16B loads from swizzled zb (no cvt).
    bf16x8 afr[2][4];
    #pragma unroll
    for (int s = 0; s < 2; ++s) {
        int row = rowBase + s * 16 + ln;
        const unsigned short* rp = zb + row * DDIM;
        int rx = row & 7;
        #pragma unroll
        for (int kc = 0; kc < 4; ++kc)
            afr[s][kc] = *reinterpret_cast<const bf16x8*>(rp + ((kc * 4 + q) ^ rx) * 8);
    }

    float m[2][4], l[2][4];
    #pragma unroll
    for (int s = 0; s < 2; ++s)
        #pragma unroll
        for (int r = 0; r < 4; ++r) { m[s][r] = -1e38f; l[s][r] = 0.f; }

#define STAGE(B, CH) do {                                                     \
        const unsigned short* sp_ = zb + (colBase + (CH) * 64) * DDIM;        \
        gload16(sp_ + (0 * 512 + tid) * 8, &lds[B][0 * 4096 + w * 512]);      \
        gload16(sp_ + (1 * 512 + tid) * 8, &lds[B][1 * 4096 + w * 512]);      \
    } while (0)

    STAGE(0, 0);
    __syncthreads();                 // compiler drains vmcnt before s_barrier

    for (int ch = 0; ch < 8; ++ch) {
        const unsigned short* buf = lds[ch & 1];
        if (ch < 7) STAGE((ch + 1) & 1, ch + 1);   // DMA prefetch under compute

        f32x4 acc[2][4];
        #pragma unroll
        for (int s = 0; s < 2; ++s)
            #pragma unroll
            for (int ct = 0; ct < 4; ++ct) acc[s][ct] = (f32x4){0.f, 0.f, 0.f, 0.f};

        #pragma unroll
        for (int ct = 0; ct < 4; ++ct) {           // 4 x 16-col tiles, 32 MFMA/chunk
            bf16x8 bfr[4];
            #pragma unroll
            for (int kc = 0; kc < 4; ++kc) {
                int slot = (q + 4 * kc) ^ (ln & 7);
                bfr[kc] = *reinterpret_cast<const bf16x8*>(
                    &buf[(ct * 16 + ln) * 128 + slot * 8]);
            }
            #pragma unroll
            for (int s = 0; s < 2; ++s)
                #pragma unroll
                for (int kc = 0; kc < 4; ++kc)
                    acc[s][ct] = __builtin_amdgcn_mfma_f32_16x16x32_bf16(
                        afr[s][kc], bfr[kc], acc[s][ct], 0, 0, 0);
        }

        const int c0 = colBase + ch * 64;
        #pragma unroll
        for (int s = 0; s < 2; ++s) {
            const int rt = rowBase + s * 16;
            #pragma unroll
            for (int ct = 0; ct < 4; ++ct) {       // diag mask, static ct (rule #20)
                if (rt == c0 + ct * 16) {
                    #pragma unroll
                    for (int r = 0; r < 4; ++r)
                        if (ln == q * 4 + r) acc[s][ct][r] = -__builtin_inff();
                }
            }
            #pragma unroll
            for (int r = 0; r < 4; ++r) {          // 64-col batched online update
                float t0 = acc[s][0][r], t1 = acc[s][1][r];
                float t2 = acc[s][2][r], t3 = acc[s][3][r];
                float mo = m[s][r];
                float mn = fmaxf(fmaxf(fmaxf(t0, t1), fmaxf(t2, t3)), mo);
                float sc = ex2(mo - mn);
                float pv = (ex2(t0 - mn) + ex2(t1 - mn)) + (ex2(t2 - mn) + ex2(t3 - mn));
                l[s][r] = fmaf(l[s][r], sc, pv);
                m[s][r] = mn;
            }
        }
        __syncthreads();
    }
#undef STAGE

    // merge (m,l) across the 16 lanes (same quad) holding each row
    #pragma unroll
    for (int s = 0; s < 2; ++s) {
        #pragma unroll
        for (int r = 0; r < 4; ++r) {
            float mm = m[s][r], ll = l[s][r];
            #pragma unroll
            for (int msk = 1; msk < 16; msk <<= 1) {
                float om = __shfl_xor(mm, msk, 64);
                float ol = __shfl_xor(ll, msk, 64);
                float mn = fmaxf(mm, om);
                ll = ll * ex2(mm - mn) + ol * ex2(om - mn);
                mm = mn;
            }
            if (ln == 0) {
                int row = rowBase + s * 16 + q * 4 + r;
                pm[cs * N_TOT + row] = mm;
                pl[cs * N_TOT + row] = ll;
            }
        }
    }

    // ---- inline finish: last col-split block for this row-block merges ----
    __syncthreads();                     // all pm/pl stores drained (vmcnt 0)
    __shared__ int amLast;
    if (tid == 0) {
        __threadfence();                 // release pm/pl device-scope
        amLast = (atomicAdd(&cnt[rb], 1) == NSPLIT - 1);
    }
    __syncthreads();
    if (amLast) {                        // block-uniform branch
        __threadfence();                 // acquire other splits' pm/pl
        float li = 0.f;
        if (tid < 256) {
            int row = rb * 256 + tid;
            float p  = 10.f * pos[row & (BHALF - 1)];
            float tp = p * LOG2E;
            float M = tp;
            float mm[NSPLIT];
            #pragma unroll
            for (int j = 0; j < NSPLIT; ++j) {
                mm[j] = pm[j * N_TOT + row];
                M = fmaxf(M, mm[j]);
            }
            float S = ex2(tp - M);       // pos appears in col 0 AND inside neg
            #pragma unroll
            for (int j = 0; j < NSPLIT; ++j)
                S += pl[j * N_TOT + row] * ex2(mm[j] - M);
            li = (M + __log2f(S)) * LN2 - p;
        }
        #pragma unroll
        for (int msk = 32; msk; msk >>= 1) li += __shfl_xor(li, msk, 64);
        __shared__ float redv[8];
        if (lane == 0) redv[w] = li;
        __syncthreads();
        if (tid == 0) {
            float t = 0.f;
            #pragma unroll
            for (int i = 0; i < 8; ++i) t += redv[i];
            atomicAdd(out, t * (1.f / 8192.f));
        }
    }
}

extern "C" void kernel_launch(void* const* d_in, const int* in_sizes, int n_in,
                              void* d_out, int out_size, void* d_ws, size_t ws_size,
                              hipStream_t stream) {
    const float* zi = (const float*)d_in[0];
    const float* zj = (const float*)d_in[1];
    float* out = (float*)d_out;
    char* ws = (char*)d_ws;

    unsigned short* zb = (unsigned short*)ws;                  // 2 MB
    float* pm  = (float*)(ws + (size_t)N_TOT * DDIM * 2);      // 512 KB
    float* pl  = pm + NSPLIT * N_TOT;                          // 512 KB
    float* pos = pl + NSPLIT * N_TOT;                          // 16 KB
    int*   cnt = (int*)(pos + BHALF);                          // 128 B

    hipLaunchKernelGGL(k_prep, dim3(512), dim3(256), 0, stream, zi, zj, zb, pos, cnt, out);
    hipLaunchKernelGGL(k_main, dim3(512), dim3(512), 0, stream, zb, pm, pl, pos, cnt, out);
}

// Round 3
// 86.154 us; speedup vs baseline: 1.3673x; 1.3673x over previous
//
#include <hip/hip_runtime.h>
#include <hip/hip_bf16.h>
#include <stdint.h>

#define N_TOT  8192
#define BHALF  4096
#define DDIM   128
#define NSPLIT 16
#define LOG2E  1.4426950408889634f
#define LN2    0.6931471805599453f

typedef short bf16x8 __attribute__((ext_vector_type(8)));
typedef float f32x4  __attribute__((ext_vector_type(4)));

__device__ __forceinline__ float ex2(float x) { return __builtin_amdgcn_exp2f(x); }

#define SCALE_C 3.798282440185f   /* sqrt(10*log2(e)): MFMA emits t = s*log2e */

__device__ __forceinline__ ushort2 cvt2(float a, float b) {
    __hip_bfloat162 h = __float22bfloat162_rn(make_float2(a, b));
    return *reinterpret_cast<ushort2*>(&h);
}

__device__ __forceinline__ bf16x8 cvt8(float4 lo, float4 hi) {
    union { bf16x8 v; ushort2 u[4]; } r;
    r.u[0] = cvt2(lo.x * SCALE_C, lo.y * SCALE_C);
    r.u[1] = cvt2(lo.z * SCALE_C, lo.w * SCALE_C);
    r.u[2] = cvt2(hi.x * SCALE_C, hi.y * SCALE_C);
    r.u[3] = cvt2(hi.z * SCALE_C, hi.w * SCALE_C);
    return r.v;
}

__device__ __forceinline__ void gload16(const void* g, void* l) {
    __builtin_amdgcn_global_load_lds(
        (const __attribute__((address_space(1))) void*)g,
        (__attribute__((address_space(3))) void*)l, 16, 0, 0);
}

// K0: z fp32 -> zb bf16 (*SCALE_C pre-folded), pre-XOR-swizzled (rule #21).
// Also: pos[r] = zi[r].zj[r] fp32 dot (16-lane shfl tree) and out init.
// NOTE: no per-block device fences anywhere -- kernel boundaries provide
// cross-XCD visibility (per-block __threadfence on gfx950 = L2 wb/inv storm,
// measured +67 us in R2).
__launch_bounds__(256)
__global__ void k_prep(const float* __restrict__ zi, const float* __restrict__ zj,
                       unsigned short* __restrict__ zb, float* __restrict__ pos,
                       float* __restrict__ out) {
    if (blockIdx.x == 0 && threadIdx.x == 0) out[0] = 0.f;  // init for k_finish atomic
    int gid = blockIdx.x * 256 + threadIdx.x;               // 8192 rows x 16 groups
    int row = gid >> 4, g = gid & 15;
    const float* rp = (row < BHALF) ? zi + row * DDIM : zj + (row - BHALF) * DDIM;
    float4 lo = *reinterpret_cast<const float4*>(rp + g * 8);
    float4 hi = *reinterpret_cast<const float4*>(rp + g * 8 + 4);
    int slot = g ^ (row & 7);
    *reinterpret_cast<bf16x8*>(&zb[row * DDIM + slot * 8]) = cvt8(lo, hi);

    if (row < BHALF) {                     // wave-uniform: blocks 0..255 only
        const float* qp = zj + row * DDIM + g * 8;
        float4 ql = *reinterpret_cast<const float4*>(qp);
        float4 qh = *reinterpret_cast<const float4*>(qp + 4);
        float d = lo.x * ql.x + lo.y * ql.y + lo.z * ql.z + lo.w * ql.w
                + hi.x * qh.x + hi.y * qh.y + hi.z * qh.z + hi.w * qh.w;
        #pragma unroll
        for (int msk = 1; msk < 16; msk <<= 1) d += __shfl_xor(d, msk, 64);
        if (g == 0) pos[row] = d;          // raw dot; x10 applied at merge
    }
}

// K1: streaming online-logsumexp over sim = (z z^T)/T rows, bf16 MFMA.
// Grid 512 = 32 row-blocks x 16 col-splits (512 cols each). Block: 8 waves
// of 32 rows. Staging is pure DMA (global_load_lds x2/thread/chunk) from the
// pre-swizzled bf16 array; online update batched over the full 64-col chunk.
__launch_bounds__(512, 4)
__global__ void k_main(const unsigned short* __restrict__ zb,
                       float* __restrict__ pm, float* __restrict__ pl) {
    __shared__ unsigned short lds[2][64 * 128];   // 2 x 16 KB
    const int tid = threadIdx.x;
    const int w = tid >> 6, lane = tid & 63;
    const int q = lane >> 4, ln = lane & 15;
    const int rb = blockIdx.x >> 4, cs = blockIdx.x & 15;
    const int rowBase = rb * 256 + w * 32;
    const int colBase = cs * 512;

    // A fragments: direct bf16 16B loads from swizzled zb (no cvt).
    bf16x8 afr[2][4];
    #pragma unroll
    for (int s = 0; s < 2; ++s) {
        int row = rowBase + s * 16 + ln;
        const unsigned short* rp = zb + row * DDIM;
        int rx = row & 7;
        #pragma unroll
        for (int kc = 0; kc < 4; ++kc)
            afr[s][kc] = *reinterpret_cast<const bf16x8*>(rp + ((kc * 4 + q) ^ rx) * 8);
    }

    float m[2][4], l[2][4];
    #pragma unroll
    for (int s = 0; s < 2; ++s)
        #pragma unroll
        for (int r = 0; r < 4; ++r) { m[s][r] = -1e38f; l[s][r] = 0.f; }

#define STAGE(B, CH) do {                                                     \
        const unsigned short* sp_ = zb + (colBase + (CH) * 64) * DDIM;        \
        gload16(sp_ + (0 * 512 + tid) * 8, &lds[B][0 * 4096 + w * 512]);      \
        gload16(sp_ + (1 * 512 + tid) * 8, &lds[B][1 * 4096 + w * 512]);      \
    } while (0)

    STAGE(0, 0);
    __syncthreads();                 // compiler drains vmcnt before s_barrier

    for (int ch = 0; ch < 8; ++ch) {
        const unsigned short* buf = lds[ch & 1];
        if (ch < 7) STAGE((ch + 1) & 1, ch + 1);   // DMA prefetch under compute

        f32x4 acc[2][4];
        #pragma unroll
        for (int s = 0; s < 2; ++s)
            #pragma unroll
            for (int ct = 0; ct < 4; ++ct) acc[s][ct] = (f32x4){0.f, 0.f, 0.f, 0.f};

        #pragma unroll
        for (int ct = 0; ct < 4; ++ct) {           // 4 x 16-col tiles, 32 MFMA/chunk
            bf16x8 bfr[4];
            #pragma unroll
            for (int kc = 0; kc < 4; ++kc) {
                int slot = (q + 4 * kc) ^ (ln & 7);
                bfr[kc] = *reinterpret_cast<const bf16x8*>(
                    &buf[(ct * 16 + ln) * 128 + slot * 8]);
            }
            #pragma unroll
            for (int s = 0; s < 2; ++s)
                #pragma unroll
                for (int kc = 0; kc < 4; ++kc)
                    acc[s][ct] = __builtin_amdgcn_mfma_f32_16x16x32_bf16(
                        afr[s][kc], bfr[kc], acc[s][ct], 0, 0, 0);
        }

        const int c0 = colBase + ch * 64;
        #pragma unroll
        for (int s = 0; s < 2; ++s) {
            const int rt = rowBase + s * 16;
            #pragma unroll
            for (int ct = 0; ct < 4; ++ct) {       // diag mask, static ct (rule #20)
                if (rt == c0 + ct * 16) {
                    #pragma unroll
                    for (int r = 0; r < 4; ++r)
                        if (ln == q * 4 + r) acc[s][ct][r] = -__builtin_inff();
                }
            }
            #pragma unroll
            for (int r = 0; r < 4; ++r) {          // 64-col batched online update
                float t0 = acc[s][0][r], t1 = acc[s][1][r];
                float t2 = acc[s][2][r], t3 = acc[s][3][r];
                float mo = m[s][r];
                float mn = fmaxf(fmaxf(fmaxf(t0, t1), fmaxf(t2, t3)), mo);
                float sc = ex2(mo - mn);
                float pv = (ex2(t0 - mn) + ex2(t1 - mn)) + (ex2(t2 - mn) + ex2(t3 - mn));
                l[s][r] = fmaf(l[s][r], sc, pv);
                m[s][r] = mn;
            }
        }
        __syncthreads();
    }
#undef STAGE

    // merge (m,l) across the 16 lanes (same quad) holding each row
    #pragma unroll
    for (int s = 0; s < 2; ++s) {
        #pragma unroll
        for (int r = 0; r < 4; ++r) {
            float mm = m[s][r], ll = l[s][r];
            #pragma unroll
            for (int msk = 1; msk < 16; msk <<= 1) {
                float om = __shfl_xor(mm, msk, 64);
                float ol = __shfl_xor(ll, msk, 64);
                float mn = fmaxf(mm, om);
                ll = ll * ex2(mm - mn) + ol * ex2(om - mn);
                mm = mn;
            }
            if (ln == 0) {
                int row = rowBase + s * 16 + q * 4 + r;
                pm[cs * N_TOT + row] = mm;
                pl[cs * N_TOT + row] = ll;
            }
        }
    }
}

// K2: per-row merge of 16 col-split partials. pos precomputed by k_prep
// (no z re-read). 64 blocks x 128 threads for latency spread.
__launch_bounds__(128)
__global__ void k_finish(const float* __restrict__ pos, const float* __restrict__ pm,
                         const float* __restrict__ pl, float* __restrict__ out) {
    int row = blockIdx.x * 128 + threadIdx.x;
    float p  = 10.f * pos[row & (BHALF - 1)];
    float tp = p * LOG2E;
    float mm[NSPLIT];
    float M = tp;
    #pragma unroll
    for (int j = 0; j < NSPLIT; ++j) {
        mm[j] = pm[j * N_TOT + row];
        M = fmaxf(M, mm[j]);
    }
    float S = ex2(tp - M);             // pos appears in col 0 AND inside neg
    #pragma unroll
    for (int j = 0; j < NSPLIT; ++j)
        S += pl[j * N_TOT + row] * ex2(mm[j] - M);
    float li = (M + __log2f(S)) * LN2 - p;
    #pragma unroll
    for (int msk = 32; msk; msk >>= 1) li += __shfl_xor(li, msk, 64);
    __shared__ float red[2];
    if ((threadIdx.x & 63) == 0) red[threadIdx.x >> 6] = li;
    __syncthreads();
    if (threadIdx.x == 0)
        atomicAdd(out, (red[0] + red[1]) * (1.f / 8192.f));
}

extern "C" void kernel_launch(void* const* d_in, const int* in_sizes, int n_in,
                              void* d_out, int out_size, void* d_ws, size_t ws_size,
                              hipStream_t stream) {
    const float* zi = (const float*)d_in[0];
    const float* zj = (const float*)d_in[1];
    float* out = (float*)d_out;
    char* ws = (char*)d_ws;

    unsigned short* zb = (unsigned short*)ws;                  // 2 MB
    float* pm  = (float*)(ws + (size_t)N_TOT * DDIM * 2);      // 512 KB
    float* pl  = pm + NSPLIT * N_TOT;                          // 512 KB
    float* pos = pl + NSPLIT * N_TOT;                          // 16 KB

    hipLaunchKernelGGL(k_prep,   dim3(512), dim3(256), 0, stream, zi, zj, zb, pos, out);
    hipLaunchKernelGGL(k_main,   dim3(512), dim3(512), 0, stream, zb, pm, pl);
    hipLaunchKernelGGL(k_finish, dim3(64),  dim3(128), 0, stream, pos, pm, pl, out);
}